// Round 1
// baseline (158.047 us; speedup 1.0000x reference)
//
#include <hip/hip_runtime.h>

constexpr int NB = 2;
constexpr int NC = 64;
constexpr int NH = 192;
constexpr int NW = 192;
constexpr int NK = 7;
constexpr int NHW = NH * NW;          // 36864
constexpr int NPIX = NB * NHW;        // 73728
constexpr float EPS = 1e-6f;

// qk intermediate layout: [b][grp][NHW][4] where grp = out_channel/4.
// grp 0..15  = q channels 0..63
// grp 16..31 = k channels 0..63 (pre-multiplied by mask)
// One float4 load = 4 consecutive channels of one pixel; consecutive lanes
// (consecutive pixels) are 16B apart -> perfectly coalesced staging loads.

// ---------------------------------------------------------------------------
// Kernel 1: layernorm + 1x1 conv as LDS-tiled GEMM. Same compute as R4;
// epilogue re-targeted at the channel-quad-interleaved layout (stores are
// 128B-contiguous per thread, strictly better coalesced than before).
// ---------------------------------------------------------------------------
__global__ __launch_bounds__(256) void qk_gemm(
    const float* __restrict__ g, const float* __restrict__ cd,
    const float* __restrict__ mask,
    const float* __restrict__ ln_w, const float* __restrict__ ln_b,
    const float* __restrict__ conv_w, const float* __restrict__ conv_b,
    float* __restrict__ qk)
{
    __shared__ float Z[65][128];
    __shared__ float WTc[33][128];

    int tid = threadIdx.x;
    int p0 = blockIdx.x * 128;
    int b  = p0 / NHW;
    int hw0 = p0 - b * NHW;

    int px = tid >> 1;
    int hf = tid & 1;
    const float* gp = g + (size_t)(b * NC + hf * 32) * NHW + (hw0 + px);
    float vals[32];
    float s = 0.f, sq = 0.f;
#pragma unroll
    for (int j = 0; j < 32; ++j) {
        float v = gp[(size_t)j * NHW];
        vals[j] = v; s += v; sq += v * v;
    }
    s  += __shfl_xor(s, 1);
    sq += __shfl_xor(sq, 1);
    float mu   = s * (1.f / 64.f);
    float rstd = rsqrtf(sq * (1.f / 64.f) - mu * mu + EPS);
#pragma unroll
    for (int j = 0; j < 32; ++j) {
        int c = hf * 32 + j;
        Z[c][px] = (vals[j] - mu) * rstd * ln_w[c] + ln_b[c];
    }
    if (hf) Z[64][px] = cd[p0 + px];

    int og = tid >> 4;
    int pg = tid & 15;
    float acc[8][8];
#pragma unroll
    for (int oi = 0; oi < 8; ++oi)
#pragma unroll
        for (int pj = 0; pj < 8; ++pj) acc[oi][pj] = 0.f;

    for (int cc = 0; cc < 65; cc += 33) {
        int nr = (65 - cc < 33) ? (65 - cc) : 33;
        __syncthreads();
        if (tid < 128) {
            int o = tid;
            for (int r = 0; r < nr; ++r)
                WTc[r][o] = conv_w[o * 65 + cc + r];
        }
        __syncthreads();
        for (int r = 0; r < nr; ++r) {
            float4 w0 = *(const float4*)&WTc[r][8 * og];
            float4 w1 = *(const float4*)&WTc[r][8 * og + 4];
            float4 z0 = *(const float4*)&Z[cc + r][8 * pg];
            float4 z1 = *(const float4*)&Z[cc + r][8 * pg + 4];
            float w8[8] = {w0.x, w0.y, w0.z, w0.w, w1.x, w1.y, w1.z, w1.w};
            float z8[8] = {z0.x, z0.y, z0.z, z0.w, z1.x, z1.y, z1.z, z1.w};
#pragma unroll
            for (int oi = 0; oi < 8; ++oi)
#pragma unroll
                for (int pj = 0; pj < 8; ++pj)
                    acc[oi][pj] = fmaf(w8[oi], z8[pj], acc[oi][pj]);
        }
    }

    int o0  = og * 8;
    int pxb = pg * 8;
    float4 ba = *(const float4*)&conv_b[o0];
    float4 bb = *(const float4*)&conv_b[o0 + 4];
    float bia[8] = {ba.x, ba.y, ba.z, ba.w, bb.x, bb.y, bb.z, bb.w};
    bool isq = (o0 < 64);
    float m8[8];
    if (!isq) {
        float4 ma = *(const float4*)&mask[p0 + pxb];
        float4 mc = *(const float4*)&mask[p0 + pxb + 4];
        m8[0]=ma.x; m8[1]=ma.y; m8[2]=ma.z; m8[3]=ma.w;
        m8[4]=mc.x; m8[5]=mc.y; m8[6]=mc.z; m8[7]=mc.w;
    }
    // store: [b][grp][NHW][4]; this thread owns grp = o0/4 and o0/4 + 1
#pragma unroll
    for (int qd = 0; qd < 2; ++qd) {
        int grp = (o0 >> 2) + qd;   // q: 0..15, k: 16..31 automatically
        float* dst = qk + ((size_t)(b * 32 + grp) * NHW + hw0 + pxb) * 4;
#pragma unroll
        for (int pj = 0; pj < 8; ++pj) {
            float vv[4];
#pragma unroll
            for (int ci = 0; ci < 4; ++ci) {
                float tv = acc[qd * 4 + ci][pj] + bia[qd * 4 + ci];
                vv[ci] = isq ? tv : tv * m8[pj];
            }
            *(float4*)(dst + pj * 4) = make_float4(vv[0], vv[1], vv[2], vv[3]);
        }
    }
}

// ---------------------------------------------------------------------------
// Kernel 2 (v5): same wave decomposition as v4 (8x16 tile, 4 waves =
// 2 row-quads x 2 channel-halves), but the channel loop is restructured into
// 8 chunks of 4 channels:
//   - k staging: 1 float4 global load per lane per 4 channels (was 4 scalar
//     loads per 1 channel), double-buffered with ~196-FMA (~600 cyc) slack.
//   - q: 1 float4 per 4 channels, prefetched one chunk ahead (was a
//     dependent strided scalar load issued right before use each channel).
//   - kst grows to 4ch planes x 2 buffers = 30.7 KB; xch[128][49] OVERLAYS
//     kst (dead after the channel loop) -> total LDS 34.1 KB, 4 blocks/CU.
//   - XCD-aware block swizzle (576 = 8*72) for k/q halo L2 reuse.
// Compute core (49 fma from a 10x24-pitch plane, 2-way bank aliasing = free)
// and the combine/softmax/aggregate epilogue are unchanged; channel
// summation order is identical -> bitwise-equal logits.
// ---------------------------------------------------------------------------
__global__ __launch_bounds__(256) void attn_tile(
    const float* __restrict__ qk,
    const float* __restrict__ cd, const float* __restrict__ sd,
    const float* __restrict__ mask, const float* __restrict__ rpb,
    float* __restrict__ out_cd, float* __restrict__ out_mask)
{
    // smem[0..7680)  : kst, 4 waves x [2 buf][4 ch][240]   (30720 B)
    //                  overlaid by xch[128][49] after the channel loop
    // smem[7680..)   : cdt[336], mt[336], rpbt[169]
    __shared__ float smem[7680 + 336 + 336 + 169];
    float* cdt  = smem + 7680;
    float* mt   = smem + 7680 + 336;
    float* rpbt = smem + 7680 + 672;

    int tid  = threadIdx.x;
    int g    = tid >> 6;
    int lane = tid & 63;
    int rq   = g & 1;
    int half = g >> 1;
    int tx   = lane & 15;
    int tyw  = lane >> 4;

    // XCD swizzle: physical XCD = blockIdx.x % 8; give each XCD a contiguous
    // 72-tile slab so neighboring tiles share halo lines in its L2.
    int bid = blockIdx.x;
    int swz = (bid & 7) * 72 + (bid >> 3);
    int bw = swz % 12;
    int t2 = swz / 12;
    int bh = t2 % 24;
    int b  = t2 / 24;
    int w0 = bw * 16, h0 = bh * 8;
    int hr0 = h0 + rq * 4;

    int h = hr0 + tyw;
    int w = w0 + tx;
    int rs = min(max(h - 3, 0), NH - NK);
    int cs = min(max(w - 3, 0), NW - NK);
    int rb  = (rs - (hr0 - 3)) * 24 + (cs - (w0 - 3));   // wave-local tile
    int rbB = (rs - (h0  - 3)) * 24 + (cs - (w0 - 3));   // block-level tile

    // ---- block-level cd/mask/rpb staging (visible after first barrier) ----
    const float* cdb = cd   + (size_t)b * NHW;
    const float* msb = mask + (size_t)b * NHW;
    for (int e = tid; e < 308; e += 256) {
        int r = e / 22, c2 = e - r * 22;
        int gr = min(max(h0 - 3 + r, 0), NH - 1);
        int gc = min(max(w0 - 3 + c2, 0), NW - 1);
        cdt[r * 24 + c2] = cdb[gr * NW + gc];
        mt [r * 24 + c2] = msb[gr * NW + gc];
    }
    if (tid < 169) rpbt[tid] = rpb[tid];

    // ---- k staging geometry: 220 slots (10x22, pitch 24), 4 rounds of 64 --
    int soff[4], slds[4]; bool sact[4];
#pragma unroll
    for (int s = 0; s < 4; ++s) {
        int e = lane + 64 * s;
        int r = e / 22, c2 = e - r * 22;
        int gr = min(max(hr0 - 3 + r, 0), NH - 1);
        int gc = min(max(w0 - 3 + c2, 0), NW - 1);
        soff[s] = (gr * NW + gc) * 4;          // float offset within a grp plane
        slds[s] = r * 24 + c2;
        sact[s] = (e < 220);
    }

    const float* kb0 = qk + (size_t)(b * 32 + 16 + half * 8) * NHW * 4;
    const float* qb0 = qk + ((size_t)(b * 32 + half * 8) * NHW + h * NW + w) * 4;

    float* kw = smem + g * 1920;   // this wave's kst: [2 buf][4 ch][240]

    float at[49];
#pragma unroll
    for (int n = 0; n < 49; ++n) at[n] = 0.f;

    // ---- prologue: stage chunk 0, prefetch q chunk 0 ----
    float4 stg[4];
    float4 qn;
#pragma unroll
    for (int s = 0; s < 4; ++s)
        stg[s] = sact[s] ? *(const float4*)(kb0 + soff[s])
                         : make_float4(0.f, 0.f, 0.f, 0.f);
    qn = *(const float4*)qb0;
#pragma unroll
    for (int s = 0; s < 4; ++s) if (sact[s]) {
        kw[0 * 240 + slds[s]] = stg[s].x;
        kw[1 * 240 + slds[s]] = stg[s].y;
        kw[2 * 240 + slds[s]] = stg[s].z;
        kw[3 * 240 + slds[s]] = stg[s].w;
    }

    // ---- main loop: 8 chunks x 4 channels, wave-synchronous dbuf ----
    for (int t = 0; t < 8; ++t) {
        float4 qv = qn;
        if (t < 7) {
            const float* kbn = kb0 + (size_t)(t + 1) * (NHW * 4);
#pragma unroll
            for (int s = 0; s < 4; ++s)
                if (sact[s]) stg[s] = *(const float4*)(kbn + soff[s]);
            qn = *(const float4*)(qb0 + (size_t)(t + 1) * (NHW * 4));
        }
        const float* kbuf = kw + (t & 1) * 960;
#pragma unroll
        for (int ccq = 0; ccq < 4; ++ccq) {
            float q = (ccq == 0) ? qv.x : (ccq == 1) ? qv.y
                    : (ccq == 2) ? qv.z : qv.w;
            const float* kt = kbuf + ccq * 240 + rb;
#pragma unroll
            for (int r = 0; r < 7; ++r)
#pragma unroll
                for (int j = 0; j < 7; ++j)
                    at[r * 7 + j] = fmaf(q, kt[r * 24 + j], at[r * 7 + j]);
        }
        if (t < 7) {
            float* nk = kw + ((t + 1) & 1) * 960;
#pragma unroll
            for (int s = 0; s < 4; ++s) if (sact[s]) {
                nk[0 * 240 + slds[s]] = stg[s].x;
                nk[1 * 240 + slds[s]] = stg[s].y;
                nk[2 * 240 + slds[s]] = stg[s].z;
                nk[3 * 240 + slds[s]] = stg[s].w;
            }
        }
    }

    // ---- combine the two channel halves + bias (xch overlays kst) ----
    float (*xch)[49] = (float(*)[49])smem;
    int pxid = (rq * 4 + tyw) * 16 + tx;   // 0..127
    __syncthreads();                        // all kst reads done before overlay
    if (half == 1) {
#pragma unroll
        for (int n = 0; n < 49; ++n) xch[pxid][n] = at[n];
    }
    __syncthreads();
    int pr = 6 - (h - rs);
    int pc = 6 - (w - cs);
    if (half == 0) {
#pragma unroll
        for (int n = 0; n < 49; ++n) at[n] += xch[pxid][n];
#pragma unroll
        for (int r = 0; r < 7; ++r)
#pragma unroll
            for (int j = 0; j < 7; ++j)
                at[r * 7 + j] += rpbt[(pr + r) * 13 + pc + j];
#pragma unroll
        for (int n = 0; n < 49; ++n) xch[pxid][n] = at[n];
    }
    __syncthreads();
    if (half == 1) {
#pragma unroll
        for (int n = 0; n < 49; ++n) at[n] = xch[pxid][n];
    }

    // ---- softmax (both halves, same logits) ----
    float mx = -1e30f;
#pragma unroll
    for (int n = 0; n < 49; ++n) mx = fmaxf(mx, at[n]);
    float sm = 0.f;
#pragma unroll
    for (int n = 0; n < 49; ++n) {
        at[n] = __expf(at[n] - mx);
        sm += at[n];
    }

    // ---- aggregate: half 0 -> cd, half 1 -> mask ----
    const float* vt = (half ? mt : cdt) + rbB;
    float sv = 0.f;
#pragma unroll
    for (int r = 0; r < 7; ++r)
#pragma unroll
        for (int j = 0; j < 7; ++j)
            sv = fmaf(at[r * 7 + j], vt[r * 24 + j], sv);
    sv /= sm;

    int p = b * NHW + h * NW + w;
    float sdc = sd[p];
    int cidx = (rq * 4 + tyw + 3) * 24 + (tx + 3);
    float mc = mt[cidx];
    if (half == 0) {
        float cdc = cdt[cidx];
        float co = sv * mc + cdc * (1.f - mc);
        if (sdc > 0.f) co = sdc;
        out_cd[p] = co;
    } else {
        out_mask[p] = (sdc > 0.f) ? mc : sv;
    }
}

extern "C" void kernel_launch(void* const* d_in, const int* in_sizes, int n_in,
                              void* d_out, int out_size, void* d_ws, size_t ws_size,
                              hipStream_t stream) {
    const float* g      = (const float*)d_in[0];
    const float* cd     = (const float*)d_in[1];
    const float* sd     = (const float*)d_in[2];
    const float* mask   = (const float*)d_in[3];
    const float* ln_w   = (const float*)d_in[4];
    const float* ln_b   = (const float*)d_in[5];
    const float* conv_w = (const float*)d_in[6];
    const float* conv_b = (const float*)d_in[7];
    const float* rpb    = (const float*)d_in[8];

    float* out   = (float*)d_out;   // [cd_out | mask_out]
    float* qkbuf = (float*)d_ws;    // NB*32*NHW*4 floats = 37.75 MB

    qk_gemm<<<dim3(NPIX / 128), dim3(256), 0, stream>>>(
        g, cd, mask, ln_w, ln_b, conv_w, conv_b, qkbuf);
    attn_tile<<<dim3(NB * 24 * 12), dim3(256), 0, stream>>>(
        qkbuf, cd, sd, mask, rpb, out, out + NPIX);
}

// Round 2
// 156.445 us; speedup vs baseline: 1.0102x; 1.0102x over previous
//
#include <hip/hip_runtime.h>

constexpr int NB = 2;
constexpr int NC = 64;
constexpr int NH = 192;
constexpr int NW = 192;
constexpr int NK = 7;
constexpr int NHW = NH * NW;          // 36864
constexpr int NPIX = NB * NHW;        // 73728
constexpr float EPS = 1e-6f;

// ---------------------------------------------------------------------------
// Kernel 1: layernorm + 1x1 conv as LDS-tiled GEMM.  (exact R4 version —
// planar qbuf/kbuf outputs; known-good at ~141.7 µs total)
// ---------------------------------------------------------------------------
__global__ __launch_bounds__(256) void qk_gemm(
    const float* __restrict__ g, const float* __restrict__ cd,
    const float* __restrict__ mask,
    const float* __restrict__ ln_w, const float* __restrict__ ln_b,
    const float* __restrict__ conv_w, const float* __restrict__ conv_b,
    float* __restrict__ qbuf, float* __restrict__ kbuf)
{
    __shared__ float Z[65][128];
    __shared__ float WTc[33][128];

    int tid = threadIdx.x;
    int p0 = blockIdx.x * 128;
    int b  = p0 / NHW;
    int hw0 = p0 - b * NHW;

    int px = tid >> 1;
    int hf = tid & 1;
    const float* gp = g + (size_t)(b * NC + hf * 32) * NHW + (hw0 + px);
    float vals[32];
    float s = 0.f, sq = 0.f;
#pragma unroll
    for (int j = 0; j < 32; ++j) {
        float v = gp[(size_t)j * NHW];
        vals[j] = v; s += v; sq += v * v;
    }
    s  += __shfl_xor(s, 1);
    sq += __shfl_xor(sq, 1);
    float mu   = s * (1.f / 64.f);
    float rstd = rsqrtf(sq * (1.f / 64.f) - mu * mu + EPS);
#pragma unroll
    for (int j = 0; j < 32; ++j) {
        int c = hf * 32 + j;
        Z[c][px] = (vals[j] - mu) * rstd * ln_w[c] + ln_b[c];
    }
    if (hf) Z[64][px] = cd[p0 + px];

    int og = tid >> 4;
    int pg = tid & 15;
    float acc[8][8];
#pragma unroll
    for (int oi = 0; oi < 8; ++oi)
#pragma unroll
        for (int pj = 0; pj < 8; ++pj) acc[oi][pj] = 0.f;

    for (int cc = 0; cc < 65; cc += 33) {
        int nr = (65 - cc < 33) ? (65 - cc) : 33;
        __syncthreads();
        if (tid < 128) {
            int o = tid;
            for (int r = 0; r < nr; ++r)
                WTc[r][o] = conv_w[o * 65 + cc + r];
        }
        __syncthreads();
        for (int r = 0; r < nr; ++r) {
            float4 w0 = *(const float4*)&WTc[r][8 * og];
            float4 w1 = *(const float4*)&WTc[r][8 * og + 4];
            float4 z0 = *(const float4*)&Z[cc + r][8 * pg];
            float4 z1 = *(const float4*)&Z[cc + r][8 * pg + 4];
            float w8[8] = {w0.x, w0.y, w0.z, w0.w, w1.x, w1.y, w1.z, w1.w};
            float z8[8] = {z0.x, z0.y, z0.z, z0.w, z1.x, z1.y, z1.z, z1.w};
#pragma unroll
            for (int oi = 0; oi < 8; ++oi)
#pragma unroll
                for (int pj = 0; pj < 8; ++pj)
                    acc[oi][pj] = fmaf(w8[oi], z8[pj], acc[oi][pj]);
        }
    }

    int o0  = og * 8;
    int pxb = pg * 8;
    float4 ba = *(const float4*)&conv_b[o0];
    float4 bb = *(const float4*)&conv_b[o0 + 4];
    float bia[8] = {ba.x, ba.y, ba.z, ba.w, bb.x, bb.y, bb.z, bb.w};
    bool isq = (o0 < 64);
    float m8[8];
    if (!isq) {
        float4 ma = *(const float4*)&mask[p0 + pxb];
        float4 mc = *(const float4*)&mask[p0 + pxb + 4];
        m8[0]=ma.x; m8[1]=ma.y; m8[2]=ma.z; m8[3]=ma.w;
        m8[4]=mc.x; m8[5]=mc.y; m8[6]=mc.z; m8[7]=mc.w;
    }
    float* base = isq ? (qbuf + (size_t)(b * NC + o0) * NHW + hw0 + pxb)
                      : (kbuf + (size_t)(b * NC + o0 - 64) * NHW + hw0 + pxb);
#pragma unroll
    for (int oi = 0; oi < 8; ++oi) {
        float v[8];
#pragma unroll
        for (int pj = 0; pj < 8; ++pj) {
            float t = acc[oi][pj] + bia[oi];
            v[pj] = isq ? t : t * m8[pj];
        }
        float* dst = base + (size_t)oi * NHW;
        *(float4*)&dst[0] = make_float4(v[0], v[1], v[2], v[3]);
        *(float4*)&dst[4] = make_float4(v[4], v[5], v[6], v[7]);
    }
}

// ---------------------------------------------------------------------------
// Kernel 2 (v6): R4 structure (8x16 tile, 4 waves = 2 row-quads x 2 channel
// halves, scalar k staging, wave-synchronous, zero barriers in the channel
// loop) with exactly three changes:
//   (a) DEPTH-2 k pipeline: loads issued at iter i are held in registers and
//       ds_written at the bottom of iter i+1 into 4 rotating wave-private
//       buffers (i&3). The vmcnt wait before the write now covers a full
//       iteration (~400+ cyc) of k-load latency instead of ~150 cyc.
//   (b) DEPTH-3 q register pipeline: kills the dependent per-channel load.
//   (c) XCD-aware bijective block swizzle (576 = 8*72) for halo L2 reuse.
// Register budget stays scalar (st regs, not float4) to avoid R5's 148-VGPR
// load-sinking failure. Channel summation order unchanged -> identical math.
// ---------------------------------------------------------------------------
__global__ __launch_bounds__(256) void attn_tile(
    const float* __restrict__ qbuf, const float* __restrict__ kbuf,
    const float* __restrict__ cd, const float* __restrict__ sd,
    const float* __restrict__ mask, const float* __restrict__ rpb,
    float* __restrict__ out_cd, float* __restrict__ out_mask)
{
    __shared__ float kst[4][4][240];       // 15.4 KB (4 waves x 4 rot bufs)
    __shared__ float cdt[14 * 24];         // 1.3 KB
    __shared__ float mt [14 * 24];         // 1.3 KB
    __shared__ float rpbt[169];
    __shared__ float xch[128][49];         // 24.5 KB   (total ~43.7 KB)

    int tid  = threadIdx.x;
    int g    = tid >> 6;
    int lane = tid & 63;
    int rq   = g & 1;
    int half = g >> 1;
    int tx   = lane & 15;
    int tyw  = lane >> 4;

    // XCD swizzle: physical XCD = bid % 8; each XCD gets a contiguous slab
    // of 72 tiles so neighbor tiles share k/q halo lines in its private L2.
    int bid = blockIdx.x;
    int swz = (bid & 7) * 72 + (bid >> 3);
    int bw = swz % 12;
    int t2 = swz / 12;
    int bh = t2 % 24;
    int b  = t2 / 24;
    int w0 = bw * 16, h0 = bh * 8;
    int hr0 = h0 + rq * 4;

    int h = hr0 + tyw;
    int w = w0 + tx;
    int rs = min(max(h - 3, 0), NH - NK);
    int cs = min(max(w - 3, 0), NW - NK);
    int rb  = (rs - (hr0 - 3)) * 24 + (cs - (w0 - 3));   // wave-local tile
    int rbB = (rs - (h0  - 3)) * 24 + (cs - (w0 - 3));   // block-level tile

    // ---- block-level cd/mask/rpb staging (visible after first barrier) ----
    const float* cdb = cd   + (size_t)b * NHW;
    const float* msb = mask + (size_t)b * NHW;
    for (int e = tid; e < 308; e += 256) {
        int r = e / 22, c2 = e - r * 22;
        int gr = min(max(h0 - 3 + r, 0), NH - 1);
        int gc = min(max(w0 - 3 + c2, 0), NW - 1);
        cdt[r * 24 + c2] = cdb[gr * NW + gc];
        mt [r * 24 + c2] = msb[gr * NW + gc];
    }
    if (tid < 169) rpbt[tid] = rpb[tid];

    // ---- k staging geometry: 220 slots (10x22, pitch 24), 4 rounds of 64 --
    int soff[4], slds[4]; bool sact[4];
#pragma unroll
    for (int s = 0; s < 4; ++s) {
        int e = lane + 64 * s;
        int r = e / 22, c2 = e - r * 22;
        int gr = min(max(hr0 - 3 + r, 0), NH - 1);
        int gc = min(max(w0 - 3 + c2, 0), NW - 1);
        soff[s] = gr * NW + gc;
        slds[s] = r * 24 + c2;
        sact[s] = (e < 220);
    }

    const float* kb = kbuf + (size_t)(b * NC + half * 32) * NHW;
    const float* qb = qbuf + (size_t)(b * NC + half * 32) * NHW + h * NW + w;

    float at[49];
#pragma unroll
    for (int n = 0; n < 49; ++n) at[n] = 0.f;

    float* kw = &kst[g][0][0];   // this wave's 4 rotating 240-float buffers

    // ---- prologue: stage ch0/ch1 into buf0/buf1, hold ch2 in regs (stC),
    //      q pipeline 3 deep ----
    float st0[4], st1[4], stC[4];
#pragma unroll
    for (int s = 0; s < 4; ++s) st0[s] = sact[s] ? kb[soff[s]] : 0.f;
#pragma unroll
    for (int s = 0; s < 4; ++s) st1[s] = sact[s] ? kb[NHW + soff[s]] : 0.f;
#pragma unroll
    for (int s = 0; s < 4; ++s) stC[s] = sact[s] ? kb[2 * NHW + soff[s]] : 0.f;
    float qA = qb[0];
    float qB = qb[NHW];
    float qC = qb[2 * (size_t)NHW];
#pragma unroll
    for (int s = 0; s < 4; ++s) if (sact[s]) kw[0 * 240 + slds[s]] = st0[s];
#pragma unroll
    for (int s = 0; s < 4; ++s) if (sact[s]) kw[1 * 240 + slds[s]] = st1[s];

    // ---- main loop: compute buf[i&3]; issue loads for ch i+3; write the
    //      regs loaded LAST iteration (ch i+2) into buf[(i+2)&3]. ----
#pragma unroll 4
    for (int i = 0; i < 32; ++i) {
        float stN[4]; float qN;
        if (i + 3 < 32) {
            const float* kbn = kb + (size_t)(i + 3) * NHW;
#pragma unroll
            for (int s = 0; s < 4; ++s)
                if (sact[s]) stN[s] = kbn[soff[s]];
            qN = qb[(size_t)(i + 3) * NHW];
        }
        const float* kt = kw + (i & 3) * 240 + rb;
        float q = qA;
#pragma unroll
        for (int r = 0; r < 7; ++r)
#pragma unroll
            for (int j = 0; j < 7; ++j)
                at[r * 7 + j] = fmaf(q, kt[r * 24 + j], at[r * 7 + j]);
        if (i + 2 < 32) {
            float* nk = kw + ((i + 2) & 3) * 240;
#pragma unroll
            for (int s = 0; s < 4; ++s) if (sact[s]) nk[slds[s]] = stC[s];
        }
#pragma unroll
        for (int s = 0; s < 4; ++s) stC[s] = stN[s];
        qA = qB; qB = qC; qC = qN;
    }

    // ---- combine the two channel halves + bias ----
    int pxid = (rq * 4 + tyw) * 16 + tx;   // 0..127
    __syncthreads();
    if (half == 1) {
#pragma unroll
        for (int n = 0; n < 49; ++n) xch[pxid][n] = at[n];
    }
    __syncthreads();
    int pr = 6 - (h - rs);
    int pc = 6 - (w - cs);
    if (half == 0) {
#pragma unroll
        for (int n = 0; n < 49; ++n) at[n] += xch[pxid][n];
#pragma unroll
        for (int r = 0; r < 7; ++r)
#pragma unroll
            for (int j = 0; j < 7; ++j)
                at[r * 7 + j] += rpbt[(pr + r) * 13 + pc + j];
#pragma unroll
        for (int n = 0; n < 49; ++n) xch[pxid][n] = at[n];
    }
    __syncthreads();
    if (half == 1) {
#pragma unroll
        for (int n = 0; n < 49; ++n) at[n] = xch[pxid][n];
    }

    // ---- softmax (both halves, same logits) ----
    float mx = -1e30f;
#pragma unroll
    for (int n = 0; n < 49; ++n) mx = fmaxf(mx, at[n]);
    float sm = 0.f;
#pragma unroll
    for (int n = 0; n < 49; ++n) {
        at[n] = __expf(at[n] - mx);
        sm += at[n];
    }

    // ---- aggregate: half 0 -> cd, half 1 -> mask ----
    const float* vt = (half ? mt : cdt) + rbB;
    float sv = 0.f;
#pragma unroll
    for (int r = 0; r < 7; ++r)
#pragma unroll
        for (int j = 0; j < 7; ++j)
            sv = fmaf(at[r * 7 + j], vt[r * 24 + j], sv);
    sv /= sm;

    int p = b * NHW + h * NW + w;
    float sdc = sd[p];
    int cidx = (rq * 4 + tyw + 3) * 24 + (tx + 3);
    float mc = mt[cidx];
    if (half == 0) {
        float cdc = cdt[cidx];
        float co = sv * mc + cdc * (1.f - mc);
        if (sdc > 0.f) co = sdc;
        out_cd[p] = co;
    } else {
        out_mask[p] = (sdc > 0.f) ? mc : sv;
    }
}

extern "C" void kernel_launch(void* const* d_in, const int* in_sizes, int n_in,
                              void* d_out, int out_size, void* d_ws, size_t ws_size,
                              hipStream_t stream) {
    const float* g      = (const float*)d_in[0];
    const float* cd     = (const float*)d_in[1];
    const float* sd     = (const float*)d_in[2];
    const float* mask   = (const float*)d_in[3];
    const float* ln_w   = (const float*)d_in[4];
    const float* ln_b   = (const float*)d_in[5];
    const float* conv_w = (const float*)d_in[6];
    const float* conv_b = (const float*)d_in[7];
    const float* rpb    = (const float*)d_in[8];

    float* out  = (float*)d_out;                 // [cd_out | mask_out]
    float* qbuf = (float*)d_ws;                  // NB*NC*NHW floats
    float* kbuf = qbuf + (size_t)NB * NC * NHW;  // NB*NC*NHW floats

    qk_gemm<<<dim3(NPIX / 128), dim3(256), 0, stream>>>(
        g, cd, mask, ln_w, ln_b, conv_w, conv_b, qbuf, kbuf);
    attn_tile<<<dim3(NB * 24 * 12), dim3(256), 0, stream>>>(
        qbuf, kbuf, cd, sd, mask, rpb, out, out + NPIX);
}

// Round 3
// 147.529 us; speedup vs baseline: 1.0713x; 1.0604x over previous
//
#include <hip/hip_runtime.h>

constexpr int NB = 2;
constexpr int NC = 64;
constexpr int NH = 192;
constexpr int NW = 192;
constexpr int NK = 7;
constexpr int NHW = NH * NW;          // 36864
constexpr int NPIX = NB * NHW;        // 73728
constexpr float EPS = 1e-6f;

// ---------------------------------------------------------------------------
// Kernel 1: layernorm + 1x1 conv as LDS-tiled GEMM.  (exact R4 version)
// ---------------------------------------------------------------------------
__global__ __launch_bounds__(256) void qk_gemm(
    const float* __restrict__ g, const float* __restrict__ cd,
    const float* __restrict__ mask,
    const float* __restrict__ ln_w, const float* __restrict__ ln_b,
    const float* __restrict__ conv_w, const float* __restrict__ conv_b,
    float* __restrict__ qbuf, float* __restrict__ kbuf)
{
    __shared__ float Z[65][128];
    __shared__ float WTc[33][128];

    int tid = threadIdx.x;
    int p0 = blockIdx.x * 128;
    int b  = p0 / NHW;
    int hw0 = p0 - b * NHW;

    int px = tid >> 1;
    int hf = tid & 1;
    const float* gp = g + (size_t)(b * NC + hf * 32) * NHW + (hw0 + px);
    float vals[32];
    float s = 0.f, sq = 0.f;
#pragma unroll
    for (int j = 0; j < 32; ++j) {
        float v = gp[(size_t)j * NHW];
        vals[j] = v; s += v; sq += v * v;
    }
    s  += __shfl_xor(s, 1);
    sq += __shfl_xor(sq, 1);
    float mu   = s * (1.f / 64.f);
    float rstd = rsqrtf(sq * (1.f / 64.f) - mu * mu + EPS);
#pragma unroll
    for (int j = 0; j < 32; ++j) {
        int c = hf * 32 + j;
        Z[c][px] = (vals[j] - mu) * rstd * ln_w[c] + ln_b[c];
    }
    if (hf) Z[64][px] = cd[p0 + px];

    int og = tid >> 4;
    int pg = tid & 15;
    float acc[8][8];
#pragma unroll
    for (int oi = 0; oi < 8; ++oi)
#pragma unroll
        for (int pj = 0; pj < 8; ++pj) acc[oi][pj] = 0.f;

    for (int cc = 0; cc < 65; cc += 33) {
        int nr = (65 - cc < 33) ? (65 - cc) : 33;
        __syncthreads();
        if (tid < 128) {
            int o = tid;
            for (int r = 0; r < nr; ++r)
                WTc[r][o] = conv_w[o * 65 + cc + r];
        }
        __syncthreads();
        for (int r = 0; r < nr; ++r) {
            float4 w0 = *(const float4*)&WTc[r][8 * og];
            float4 w1 = *(const float4*)&WTc[r][8 * og + 4];
            float4 z0 = *(const float4*)&Z[cc + r][8 * pg];
            float4 z1 = *(const float4*)&Z[cc + r][8 * pg + 4];
            float w8[8] = {w0.x, w0.y, w0.z, w0.w, w1.x, w1.y, w1.z, w1.w};
            float z8[8] = {z0.x, z0.y, z0.z, z0.w, z1.x, z1.y, z1.z, z1.w};
#pragma unroll
            for (int oi = 0; oi < 8; ++oi)
#pragma unroll
                for (int pj = 0; pj < 8; ++pj)
                    acc[oi][pj] = fmaf(w8[oi], z8[pj], acc[oi][pj]);
        }
    }

    int o0  = og * 8;
    int pxb = pg * 8;
    float4 ba = *(const float4*)&conv_b[o0];
    float4 bb = *(const float4*)&conv_b[o0 + 4];
    float bia[8] = {ba.x, ba.y, ba.z, ba.w, bb.x, bb.y, bb.z, bb.w};
    bool isq = (o0 < 64);
    float m8[8];
    if (!isq) {
        float4 ma = *(const float4*)&mask[p0 + pxb];
        float4 mc = *(const float4*)&mask[p0 + pxb + 4];
        m8[0]=ma.x; m8[1]=ma.y; m8[2]=ma.z; m8[3]=ma.w;
        m8[4]=mc.x; m8[5]=mc.y; m8[6]=mc.z; m8[7]=mc.w;
    }
    float* base = isq ? (qbuf + (size_t)(b * NC + o0) * NHW + hw0 + pxb)
                      : (kbuf + (size_t)(b * NC + o0 - 64) * NHW + hw0 + pxb);
#pragma unroll
    for (int oi = 0; oi < 8; ++oi) {
        float v[8];
#pragma unroll
        for (int pj = 0; pj < 8; ++pj) {
            float t = acc[oi][pj] + bia[oi];
            v[pj] = isq ? t : t * m8[pj];
        }
        float* dst = base + (size_t)oi * NHW;
        *(float4*)&dst[0] = make_float4(v[0], v[1], v[2], v[3]);
        *(float4*)&dst[4] = make_float4(v[4], v[5], v[6], v[7]);
    }
}

// ---------------------------------------------------------------------------
// Kernel 2 (v7): R4 per-wave body, but 8 waves/block = 2 row-quads x
// 4 CHANNEL-QUARTERS (16 ch/wave).  Whole 576-block grid is co-resident
// (43.8 KB LDS -> 3 blocks/CU >= 2.25 needed): 4.5 waves/SIMD, 2x R4's TLP.
// Per-wave schedule identical to R4 (depth-1 k staging, 2 rotating wave-
// private buffers, zero barriers in the channel loop, scalar loads) to stay
// in the 68-VGPR-class regime; only adds a depth-2 q register pipeline.
// Logits combined Q3->Q2->Q1->Q0 via xch (4 barriers); quarters 0/1 do
// softmax + cd/mask aggregation. XCD-aware bijective swizzle kept (proven
// 4x FETCH reduction in R5/R6).
// ---------------------------------------------------------------------------
__global__ __launch_bounds__(512) void attn_tile(
    const float* __restrict__ qbuf, const float* __restrict__ kbuf,
    const float* __restrict__ cd, const float* __restrict__ sd,
    const float* __restrict__ mask, const float* __restrict__ rpb,
    float* __restrict__ out_cd, float* __restrict__ out_mask)
{
    __shared__ float kst[8][2][240];       // 15.4 KB (8 waves x 2 rot bufs)
    __shared__ float cdt[14 * 24];         // 1.3 KB
    __shared__ float mt [14 * 24];         // 1.3 KB
    __shared__ float rpbt[169];
    __shared__ float xch[128][49];         // 24.5 KB   (total 43.8 KB)

    int tid  = threadIdx.x;
    int g    = tid >> 6;
    int lane = tid & 63;
    int rq   = g & 1;
    int quar = g >> 1;          // 0..3, 16 channels each
    int tx   = lane & 15;
    int tyw  = lane >> 4;

    // XCD swizzle: physical XCD = bid % 8; contiguous 72-tile slab per XCD.
    int bid = blockIdx.x;
    int swz = (bid & 7) * 72 + (bid >> 3);
    int bw = swz % 12;
    int t2 = swz / 12;
    int bh = t2 % 24;
    int b  = t2 / 24;
    int w0 = bw * 16, h0 = bh * 8;
    int hr0 = h0 + rq * 4;

    int h = hr0 + tyw;
    int w = w0 + tx;
    int rs = min(max(h - 3, 0), NH - NK);
    int cs = min(max(w - 3, 0), NW - NK);
    int rb  = (rs - (hr0 - 3)) * 24 + (cs - (w0 - 3));   // wave-local tile
    int rbB = (rs - (h0  - 3)) * 24 + (cs - (w0 - 3));   // block-level tile

    // ---- block-level cd/mask/rpb staging (visible after first barrier) ----
    const float* cdb = cd   + (size_t)b * NHW;
    const float* msb = mask + (size_t)b * NHW;
    for (int e = tid; e < 308; e += 512) {
        int r = e / 22, c2 = e - r * 22;
        int gr = min(max(h0 - 3 + r, 0), NH - 1);
        int gc = min(max(w0 - 3 + c2, 0), NW - 1);
        cdt[r * 24 + c2] = cdb[gr * NW + gc];
        mt [r * 24 + c2] = msb[gr * NW + gc];
    }
    if (tid < 169) rpbt[tid] = rpb[tid];

    // ---- k staging geometry: 220 slots (10x22, pitch 24), 4 rounds of 64 --
    int soff[4], slds[4]; bool sact[4];
#pragma unroll
    for (int s = 0; s < 4; ++s) {
        int e = lane + 64 * s;
        int r = e / 22, c2 = e - r * 22;
        int gr = min(max(hr0 - 3 + r, 0), NH - 1);
        int gc = min(max(w0 - 3 + c2, 0), NW - 1);
        soff[s] = gr * NW + gc;
        slds[s] = r * 24 + c2;
        sact[s] = (e < 220);
    }

    const float* kb = kbuf + (size_t)(b * NC + quar * 16) * NHW;
    const float* qb = qbuf + (size_t)(b * NC + quar * 16) * NHW + h * NW + w;

    float at[49];
#pragma unroll
    for (int n = 0; n < 49; ++n) at[n] = 0.f;

    float st[4];
#pragma unroll
    for (int s = 0; s < 4; ++s) st[s] = sact[s] ? kb[soff[s]] : 0.f;
    float* k0 = kst[g][0];
    float* k1 = kst[g][1];
#pragma unroll
    for (int s = 0; s < 4; ++s) if (sact[s]) k0[slds[s]] = st[s];
    float qA = qb[0];
    float qB = qb[NHW];

    // ---- channel loop: 16 iterations, wave-synchronous double buffer ----
    for (int i = 0; i < 16; ++i) {
        if (i + 1 < 16) {
            const float* kb2 = kb + (size_t)(i + 1) * NHW;
#pragma unroll
            for (int s = 0; s < 4; ++s) st[s] = sact[s] ? kb2[soff[s]] : 0.f;
        }
        float q = qA;
        qA = qB;
        if (i + 2 < 16) qB = qb[(size_t)(i + 2) * NHW];
        const float* kt = ((i & 1) ? k1 : k0) + rb;
#pragma unroll
        for (int r = 0; r < 7; ++r)
#pragma unroll
            for (int j = 0; j < 7; ++j)
                at[r * 7 + j] = fmaf(q, kt[r * 24 + j], at[r * 7 + j]);
        if (i + 1 < 16) {
            float* nk = (i & 1) ? k0 : k1;
#pragma unroll
            for (int s = 0; s < 4; ++s) if (sact[s]) nk[slds[s]] = st[s];
        }
    }

    // ---- combine four channel quarters (serial xch reduction) + bias ----
    int pxid = (rq * 4 + tyw) * 16 + tx;   // 0..127
    if (quar == 3) {
#pragma unroll
        for (int n = 0; n < 49; ++n) xch[pxid][n] = at[n];
    }
    __syncthreads();
    if (quar == 2) {
#pragma unroll
        for (int n = 0; n < 49; ++n) xch[pxid][n] += at[n];
    }
    __syncthreads();
    if (quar == 1) {
#pragma unroll
        for (int n = 0; n < 49; ++n) xch[pxid][n] += at[n];
    }
    __syncthreads();
    int pr = 6 - (h - rs);
    int pc = 6 - (w - cs);
    if (quar == 0) {
#pragma unroll
        for (int n = 0; n < 49; ++n) at[n] += xch[pxid][n];
#pragma unroll
        for (int r = 0; r < 7; ++r)
#pragma unroll
            for (int j = 0; j < 7; ++j)
                at[r * 7 + j] += rpbt[(pr + r) * 13 + pc + j];
#pragma unroll
        for (int n = 0; n < 49; ++n) xch[pxid][n] = at[n];
    }
    __syncthreads();
    if (quar >= 2) return;      // no further barriers below
    if (quar == 1) {
#pragma unroll
        for (int n = 0; n < 49; ++n) at[n] = xch[pxid][n];
    }

    // ---- softmax (quarters 0/1, same logits) ----
    float mx = -1e30f;
#pragma unroll
    for (int n = 0; n < 49; ++n) mx = fmaxf(mx, at[n]);
    float sm = 0.f;
#pragma unroll
    for (int n = 0; n < 49; ++n) {
        at[n] = __expf(at[n] - mx);
        sm += at[n];
    }

    // ---- aggregate: quarter 0 -> cd, quarter 1 -> mask ----
    const float* vt = (quar ? mt : cdt) + rbB;
    float sv = 0.f;
#pragma unroll
    for (int r = 0; r < 7; ++r)
#pragma unroll
        for (int j = 0; j < 7; ++j)
            sv = fmaf(at[r * 7 + j], vt[r * 24 + j], sv);
    sv /= sm;

    int p = b * NHW + h * NW + w;
    float sdc = sd[p];
    int cidx = (rq * 4 + tyw + 3) * 24 + (tx + 3);
    float mc = mt[cidx];
    if (quar == 0) {
        float cdc = cdt[cidx];
        float co = sv * mc + cdc * (1.f - mc);
        if (sdc > 0.f) co = sdc;
        out_cd[p] = co;
    } else {
        out_mask[p] = (sdc > 0.f) ? mc : sv;
    }
}

extern "C" void kernel_launch(void* const* d_in, const int* in_sizes, int n_in,
                              void* d_out, int out_size, void* d_ws, size_t ws_size,
                              hipStream_t stream) {
    const float* g      = (const float*)d_in[0];
    const float* cd     = (const float*)d_in[1];
    const float* sd     = (const float*)d_in[2];
    const float* mask   = (const float*)d_in[3];
    const float* ln_w   = (const float*)d_in[4];
    const float* ln_b   = (const float*)d_in[5];
    const float* conv_w = (const float*)d_in[6];
    const float* conv_b = (const float*)d_in[7];
    const float* rpb    = (const float*)d_in[8];

    float* out  = (float*)d_out;                 // [cd_out | mask_out]
    float* qbuf = (float*)d_ws;                  // NB*NC*NHW floats
    float* kbuf = qbuf + (size_t)NB * NC * NHW;  // NB*NC*NHW floats

    qk_gemm<<<dim3(NPIX / 128), dim3(256), 0, stream>>>(
        g, cd, mask, ln_w, ln_b, conv_w, conv_b, qbuf, kbuf);
    attn_tile<<<dim3(NB * 24 * 12), dim3(512), 0, stream>>>(
        qbuf, kbuf, cd, sd, mask, rpb, out, out + NPIX);
}

// Round 4
// 135.011 us; speedup vs baseline: 1.1706x; 1.0927x over previous
//
#include <hip/hip_runtime.h>

constexpr int NB = 2;
constexpr int NC = 64;
constexpr int NH = 192;
constexpr int NW = 192;
constexpr int NK = 7;
constexpr int NHW = NH * NW;          // 36864
constexpr int NPIX = NB * NHW;        // 73728
constexpr float EPS = 1e-6f;

// ---------------------------------------------------------------------------
// Kernel 1: layernorm + 1x1 conv as LDS-tiled GEMM.  (exact R4 version)
// ---------------------------------------------------------------------------
__global__ __launch_bounds__(256) void qk_gemm(
    const float* __restrict__ g, const float* __restrict__ cd,
    const float* __restrict__ mask,
    const float* __restrict__ ln_w, const float* __restrict__ ln_b,
    const float* __restrict__ conv_w, const float* __restrict__ conv_b,
    float* __restrict__ qbuf, float* __restrict__ kbuf)
{
    __shared__ float Z[65][128];
    __shared__ float WTc[33][128];

    int tid = threadIdx.x;
    int p0 = blockIdx.x * 128;
    int b  = p0 / NHW;
    int hw0 = p0 - b * NHW;

    int px = tid >> 1;
    int hf = tid & 1;
    const float* gp = g + (size_t)(b * NC + hf * 32) * NHW + (hw0 + px);
    float vals[32];
    float s = 0.f, sq = 0.f;
#pragma unroll
    for (int j = 0; j < 32; ++j) {
        float v = gp[(size_t)j * NHW];
        vals[j] = v; s += v; sq += v * v;
    }
    s  += __shfl_xor(s, 1);
    sq += __shfl_xor(sq, 1);
    float mu   = s * (1.f / 64.f);
    float rstd = rsqrtf(sq * (1.f / 64.f) - mu * mu + EPS);
#pragma unroll
    for (int j = 0; j < 32; ++j) {
        int c = hf * 32 + j;
        Z[c][px] = (vals[j] - mu) * rstd * ln_w[c] + ln_b[c];
    }
    if (hf) Z[64][px] = cd[p0 + px];

    int og = tid >> 4;
    int pg = tid & 15;
    float acc[8][8];
#pragma unroll
    for (int oi = 0; oi < 8; ++oi)
#pragma unroll
        for (int pj = 0; pj < 8; ++pj) acc[oi][pj] = 0.f;

    for (int cc = 0; cc < 65; cc += 33) {
        int nr = (65 - cc < 33) ? (65 - cc) : 33;
        __syncthreads();
        if (tid < 128) {
            int o = tid;
            for (int r = 0; r < nr; ++r)
                WTc[r][o] = conv_w[o * 65 + cc + r];
        }
        __syncthreads();
        for (int r = 0; r < nr; ++r) {
            float4 w0 = *(const float4*)&WTc[r][8 * og];
            float4 w1 = *(const float4*)&WTc[r][8 * og + 4];
            float4 z0 = *(const float4*)&Z[cc + r][8 * pg];
            float4 z1 = *(const float4*)&Z[cc + r][8 * pg + 4];
            float w8[8] = {w0.x, w0.y, w0.z, w0.w, w1.x, w1.y, w1.z, w1.w};
            float z8[8] = {z0.x, z0.y, z0.z, z0.w, z1.x, z1.y, z1.z, z1.w};
#pragma unroll
            for (int oi = 0; oi < 8; ++oi)
#pragma unroll
                for (int pj = 0; pj < 8; ++pj)
                    acc[oi][pj] = fmaf(w8[oi], z8[pj], acc[oi][pj]);
        }
    }

    int o0  = og * 8;
    int pxb = pg * 8;
    float4 ba = *(const float4*)&conv_b[o0];
    float4 bb = *(const float4*)&conv_b[o0 + 4];
    float bia[8] = {ba.x, ba.y, ba.z, ba.w, bb.x, bb.y, bb.z, bb.w};
    bool isq = (o0 < 64);
    float m8[8];
    if (!isq) {
        float4 ma = *(const float4*)&mask[p0 + pxb];
        float4 mc = *(const float4*)&mask[p0 + pxb + 4];
        m8[0]=ma.x; m8[1]=ma.y; m8[2]=ma.z; m8[3]=ma.w;
        m8[4]=mc.x; m8[5]=mc.y; m8[6]=mc.z; m8[7]=mc.w;
    }
    float* base = isq ? (qbuf + (size_t)(b * NC + o0) * NHW + hw0 + pxb)
                      : (kbuf + (size_t)(b * NC + o0 - 64) * NHW + hw0 + pxb);
#pragma unroll
    for (int oi = 0; oi < 8; ++oi) {
        float v[8];
#pragma unroll
        for (int pj = 0; pj < 8; ++pj) {
            float t = acc[oi][pj] + bia[oi];
            v[pj] = isq ? t : t * m8[pj];
        }
        float* dst = base + (size_t)oi * NHW;
        *(float4*)&dst[0] = make_float4(v[0], v[1], v[2], v[3]);
        *(float4*)&dst[4] = make_float4(v[4], v[5], v[6], v[7]);
    }
}

// ---------------------------------------------------------------------------
// Kernel 2 (v8): LDS-read-throughput attack via 2-pixel horizontal blocking.
//   - wave = 8 rows x 8 col-pairs = 128 px (2 px/lane, cols 2tx, 2tx+1).
//   - 4 waves = 4 channel QUARTERS over the SAME 8x16 px tile; 576 blocks
//     (2.25 waves/SIMD, R4's proven TLP).
//   - per row the pair's two 7-wide windows are served by ONE 8-float read
//     (4 ds_read2) -> core-loop LDS instructions per px*ch HALVED (0.44->0.23).
//   - pixel1 uses v[j+1] (interior; d==1 for all lanes in bw 1..10 -> wave-
//     uniform fast path, zero selects) or d? v[j+1]:v[j] (edge blocks only).
//   - cross-quarter combine via xch[49][2][64] indexed by raw lane: every
//     access is 64 consecutive dwords -> conflict-free (pxid*49 layout would
//     be 4-way with 2px/lane).
//   - kst wave-private double-buffer, zero barriers in channel loop (R4
//     schedule, depth-1 staging; now ~2x FMA slack per iteration).
//   - VGPR ~140 expected (98 accumulators, statically indexed) — accepted;
//     pressure is accumulator-driven, not scheduling-driven (R5/R6 mode).
// ---------------------------------------------------------------------------
struct TrueC  { static constexpr bool value = true;  };
struct FalseC { static constexpr bool value = false; };

__global__ __launch_bounds__(256) void attn_tile(
    const float* __restrict__ qbuf, const float* __restrict__ kbuf,
    const float* __restrict__ cd, const float* __restrict__ sd,
    const float* __restrict__ mask, const float* __restrict__ rpb,
    float* __restrict__ out_cd, float* __restrict__ out_mask)
{
    __shared__ float kst[4][2][350];   // 11.2 KB: 4 waves x 2 bufs x 14x25
    __shared__ float xch[49][2][64];   // 24.5 KB, conflict-free combine
    __shared__ float cdt[350];         // 14 x 22 @ pitch 25
    __shared__ float mt [350];
    __shared__ float rpbt[169];        // total ~38.8 KB

    int tid  = threadIdx.x;
    int g    = tid >> 6;       // channel quarter 0..3 (16 ch each)
    int lane = tid & 63;
    int tx   = lane & 7;       // col-pair index
    int ty   = lane >> 3;      // row 0..7

    // XCD swizzle (proven 4x FETCH cut): contiguous 72-tile slab per XCD.
    int bid = blockIdx.x;
    int swz = (bid & 7) * 72 + (bid >> 3);
    int bw = swz % 12;
    int t2 = swz / 12;
    int bh = t2 % 24;
    int b  = t2 / 24;
    int w0 = bw * 16, h0 = bh * 8;

    int h   = h0 + ty;
    int wpx = w0 + 2 * tx;                      // pixel0; pixel1 = wpx+1
    int rs  = min(max(h - 3, 0), NH - NK);
    int cs0 = min(max(wpx - 3, 0), NW - NK);
    int cs1 = min(max(wpx - 2, 0), NW - NK);
    int d1  = cs1 - cs0;                        // 0 or 1; 1 for bw in 1..10
    // tile coords: tile spans rows h0-3.., cols w0-3.., pitch 25
    int ktb = (rs - (h0 - 3)) * 25 + (cs0 - (w0 - 3));

    // ---- block-level cd/mask/rpb staging (14x22 tile, 308 elems) ----
    const float* cdb = cd   + (size_t)b * NHW;
    const float* msb = mask + (size_t)b * NHW;
    for (int e = tid; e < 308; e += 256) {
        int r = e / 22, c = e - r * 22;
        int gr = min(max(h0 - 3 + r, 0), NH - 1);
        int gc = min(max(w0 - 3 + c, 0), NW - 1);
        cdt[r * 25 + c] = cdb[gr * NW + gc];
        mt [r * 25 + c] = msb[gr * NW + gc];
    }
    if (tid < 169) rpbt[tid] = rpb[tid];

    // ---- k staging slots: 308 elems (14x22), 5 rounds of 64 ----
    int soff[5], slds[5];
#pragma unroll
    for (int s = 0; s < 5; ++s) {
        int e = lane + 64 * s;
        int r = e / 22, c = e - r * 22;
        int gr = min(max(h0 - 3 + r, 0), NH - 1);
        int gc = min(max(w0 - 3 + c, 0), NW - 1);
        bool act = e < 308;
        soff[s] = act ? (gr * NW + gc) : 0;     // safe addr for inactive
        slds[s] = act ? (r * 25 + c) : 348;     // dummy slot for inactive
    }

    const float* kb = kbuf + (size_t)(b * NC + g * 16) * NHW;
    const float* qb = qbuf + (size_t)(b * NC + g * 16) * NHW + h * NW + wpx;

    float at0[49], at1[49];
#pragma unroll
    for (int n = 0; n < 49; ++n) { at0[n] = 0.f; at1[n] = 0.f; }

    float* k0 = &kst[g][0][0];
    float* k1 = &kst[g][1][0];

    auto run = [&](auto edgec) {
        constexpr bool EDGE = decltype(edgec)::value;
        float st[5];
#pragma unroll
        for (int s = 0; s < 5; ++s) st[s] = kb[soff[s]];
#pragma unroll
        for (int s = 0; s < 5; ++s) k0[slds[s]] = st[s];
        float2 qA = *(const float2*)qb;
        float2 qB = *(const float2*)(qb + NHW);
        for (int i = 0; i < 16; ++i) {
            if (i + 1 < 16) {
                const float* kb2 = kb + (size_t)(i + 1) * NHW;
#pragma unroll
                for (int s = 0; s < 5; ++s) st[s] = kb2[soff[s]];
            }
            float2 q = qA; qA = qB;
            if (i + 2 < 16) qB = *(const float2*)(qb + (size_t)(i + 2) * NHW);
            const float* kt = ((i & 1) ? k1 : k0) + ktb;
#pragma unroll
            for (int r = 0; r < 7; ++r) {
                const float* kr = kt + r * 25;
                float v[8];
#pragma unroll
                for (int j = 0; j < 8; ++j) v[j] = kr[j];
#pragma unroll
                for (int j = 0; j < 7; ++j)
                    at0[r * 7 + j] = fmaf(q.x, v[j], at0[r * 7 + j]);
#pragma unroll
                for (int j = 0; j < 7; ++j) {
                    float u;
                    if constexpr (EDGE) u = d1 ? v[j + 1] : v[j];
                    else                u = v[j + 1];
                    at1[r * 7 + j] = fmaf(q.y, u, at1[r * 7 + j]);
                }
            }
            if (i + 1 < 16) {
                float* nk = (i & 1) ? k0 : k1;
#pragma unroll
                for (int s = 0; s < 5; ++s) nk[slds[s]] = st[s];
            }
        }
    };
    if (bw == 0 || bw == 11) run(TrueC{}); else run(FalseC{});

    // ---- combine 4 quarters via xch[n][pp][lane] (conflict-free) ----
    __syncthreads();                       // also publishes cdt/mt/rpbt
    if (g == 3) {
#pragma unroll
        for (int n = 0; n < 49; ++n) {
            xch[n][0][lane] = at0[n]; xch[n][1][lane] = at1[n];
        }
    }
    __syncthreads();
    if (g == 2) {
#pragma unroll
        for (int n = 0; n < 49; ++n) {
            xch[n][0][lane] += at0[n]; xch[n][1][lane] += at1[n];
        }
    }
    __syncthreads();
    if (g == 0) {
#pragma unroll
        for (int n = 0; n < 49; ++n) {
            xch[n][0][lane] += at0[n]; xch[n][1][lane] += at1[n];
        }
    }
    __syncthreads();
    int pr  = 6 - (h - rs);
    int pc0 = 6 - (wpx - cs0);
    int pc1 = 6 - (wpx + 1 - cs1);
    if (g == 1) {
#pragma unroll
        for (int n = 0; n < 49; ++n) {
            at0[n] += xch[n][0][lane]; at1[n] += xch[n][1][lane];
        }
#pragma unroll
        for (int r = 0; r < 7; ++r)
#pragma unroll
            for (int j = 0; j < 7; ++j) {
                at0[r * 7 + j] += rpbt[(pr + r) * 13 + pc0 + j];
                at1[r * 7 + j] += rpbt[(pr + r) * 13 + pc1 + j];
            }
#pragma unroll
        for (int n = 0; n < 49; ++n) {
            xch[n][0][lane] = at0[n]; xch[n][1][lane] = at1[n];
        }
    }
    __syncthreads();
    if (g == 0) {
#pragma unroll
        for (int n = 0; n < 49; ++n) {
            at0[n] = xch[n][0][lane]; at1[n] = xch[n][1][lane];
        }
    }
    if (g >= 2) return;

    // ---- softmax (quarters 0/1 hold identical full logits) ----
    float mx0 = -1e30f, mx1 = -1e30f;
#pragma unroll
    for (int n = 0; n < 49; ++n) {
        mx0 = fmaxf(mx0, at0[n]); mx1 = fmaxf(mx1, at1[n]);
    }
    float sm0 = 0.f, sm1 = 0.f;
#pragma unroll
    for (int n = 0; n < 49; ++n) {
        at0[n] = __expf(at0[n] - mx0); sm0 += at0[n];
        at1[n] = __expf(at1[n] - mx1); sm1 += at1[n];
    }

    // ---- aggregate: quarter 0 -> cd, quarter 1 -> mask (shared window) ----
    const float* vt = (g ? mt : cdt) + ktb;
    float sv0 = 0.f, sv1 = 0.f;
#pragma unroll
    for (int r = 0; r < 7; ++r) {
        const float* vr = vt + r * 25;
        float v[8];
#pragma unroll
        for (int j = 0; j < 8; ++j) v[j] = vr[j];
#pragma unroll
        for (int j = 0; j < 7; ++j) {
            sv0 = fmaf(at0[r * 7 + j], v[j], sv0);
            float u = d1 ? v[j + 1] : v[j];
            sv1 = fmaf(at1[r * 7 + j], u, sv1);
        }
    }
    sv0 /= sm0; sv1 /= sm1;

    int p = b * NHW + h * NW + wpx;
    float2 sdv = *(const float2*)(sd + p);
    int ci = (ty + 3) * 25 + (2 * tx + 3);
    float mc0 = mt[ci], mc1 = mt[ci + 1];
    if (g == 0) {
        float cdc0 = cdt[ci], cdc1 = cdt[ci + 1];
        float co0 = sv0 * mc0 + cdc0 * (1.f - mc0);
        float co1 = sv1 * mc1 + cdc1 * (1.f - mc1);
        if (sdv.x > 0.f) co0 = sdv.x;
        if (sdv.y > 0.f) co1 = sdv.y;
        *(float2*)(out_cd + p) = make_float2(co0, co1);
    } else {
        float o0 = (sdv.x > 0.f) ? mc0 : sv0;
        float o1 = (sdv.y > 0.f) ? mc1 : sv1;
        *(float2*)(out_mask + p) = make_float2(o0, o1);
    }
}

extern "C" void kernel_launch(void* const* d_in, const int* in_sizes, int n_in,
                              void* d_out, int out_size, void* d_ws, size_t ws_size,
                              hipStream_t stream) {
    const float* g      = (const float*)d_in[0];
    const float* cd     = (const float*)d_in[1];
    const float* sd     = (const float*)d_in[2];
    const float* mask   = (const float*)d_in[3];
    const float* ln_w   = (const float*)d_in[4];
    const float* ln_b   = (const float*)d_in[5];
    const float* conv_w = (const float*)d_in[6];
    const float* conv_b = (const float*)d_in[7];
    const float* rpb    = (const float*)d_in[8];

    float* out  = (float*)d_out;                 // [cd_out | mask_out]
    float* qbuf = (float*)d_ws;                  // NB*NC*NHW floats
    float* kbuf = qbuf + (size_t)NB * NC * NHW;  // NB*NC*NHW floats

    qk_gemm<<<dim3(NPIX / 128), dim3(256), 0, stream>>>(
        g, cd, mask, ln_w, ln_b, conv_w, conv_b, qbuf, kbuf);
    attn_tile<<<dim3(NB * 24 * 12), dim3(256), 0, stream>>>(
        qbuf, kbuf, cd, sd, mask, rpb, out, out + NPIX);
}